// Round 4
// baseline (79.544 us; speedup 1.0000x reference)
//
#include <hip/hip_runtime.h>
#include <hip/hip_bf16.h>

typedef float f4 __attribute__((ext_vector_type(4)));
typedef float f32x4 __attribute__((ext_vector_type(4)));
typedef short bf16x8 __attribute__((ext_vector_type(8)));

#define D 2048
#define RANK 16

__device__ __forceinline__ short bf16_of(float x) {
    return __builtin_bit_cast(short, __float2bfloat16(x));
}

__device__ __forceinline__ bf16x8 cvt8(f4 lo, f4 hi) {
    bf16x8 r;
    r[0] = bf16_of(lo.x); r[1] = bf16_of(lo.y);
    r[2] = bf16_of(lo.z); r[3] = bf16_of(lo.w);
    r[4] = bf16_of(hi.x); r[5] = bf16_of(hi.y);
    r[6] = bf16_of(hi.z); r[7] = bf16_of(hi.w);
    return r;
}

// out = h @ (A@B)^T factored through rank-16, MFMA-based.
// Block: 256 thr = 4 waves. wave wt=w>>1 owns a 16-row tile, half=w&1 its
// d-half (phase1) / e-half (phase2). One barrier per block total.
//
// Phase1 computes T^T = B_mat · h^T so the MFMA D-layout lands exactly in
// the layout phase2's B-operand wants (after the LDS half-merge):
//   D lane l, reg i: T^T[rank=(l>>4)*4+i][row=l&15]  (m89-verified C/D map)
// Phase2: out-tile = A_mat(16e x 16r) · T, K=16 zero-padded to 32: lanes
// l>=32 carry zeroed b-frag slots, so those k-slices contribute 0.
__global__ __launch_bounds__(256, 2)
void lora_mfma(const float* __restrict__ h, const float* __restrict__ A,
               const float* __restrict__ B, float* __restrict__ out) {
    const int tid  = threadIdx.x;
    const int wave = tid >> 6;
    const int lane = tid & 63;
    const int m16  = lane & 15;
    const int kg   = lane >> 4;        // k-slot group 0..3
    const int wt   = wave >> 1;        // tile-in-block
    const int half = wave & 1;         // d-half (p1) / e-half (p2)
    const long row0 = ((long)blockIdx.x * 2 + wt) * 16;

    __shared__ f4 ldsT[2][2][16][4];   // [tile][half][row][rank-quad]

    // ---------------- phase 1: T^T = B · h^T over this d-half -------------
    // a-frag: B[rank=m16][d0 + kg*8 + j]   (8 consecutive fp32, 32B aligned)
    // b-frag: h[row0+m16][d0 + kg*8 + j]
    const float* pB = B + (long)m16 * D + half * 1024 + kg * 8;
    const float* ph = h + (row0 + m16) * D + half * 1024 + kg * 8;

    f32x4 acc = {0.f, 0.f, 0.f, 0.f};
#pragma unroll 4
    for (int s = 0; s < 32; ++s) {
        f4 a0 = *(const f4*)(pB + s * 32);
        f4 a1 = *(const f4*)(pB + s * 32 + 4);
        f4 b0 = *(const f4*)(ph + s * 32);
        f4 b1 = *(const f4*)(ph + s * 32 + 4);
        acc = __builtin_amdgcn_mfma_f32_16x16x32_bf16(
            cvt8(a0, a1), cvt8(b0, b1), acc, 0, 0, 0);
    }
    // lane l holds T[row=m16][rank=kg*4+i], i=0..3 -> one f4 LDS write
    ldsT[wt][half][m16][kg] = acc;
    __syncthreads();

    // ---------------- T b-frag for phase2 (constant across e-loop) --------
    // lane l<32 needs T[row=m16][rank = kg*8 + j], j=0..7, halves summed
    bf16x8 tf = {0, 0, 0, 0, 0, 0, 0, 0};
    if (lane < 32) {
        f4 t0 = ldsT[wt][0][m16][kg * 2]     + ldsT[wt][1][m16][kg * 2];
        f4 t1 = ldsT[wt][0][m16][kg * 2 + 1] + ldsT[wt][1][m16][kg * 2 + 1];
        tf = cvt8(t0, t1);
    }

    // ---------------- phase 2: out rows over this e-half ------------------
    // per 16-e tile: a-frag = A[e0+m16][k], k = kg*8+j (clamped for kg>=2,
    // those slots are killed by tf==0); D: lane stores 4 consecutive e.
    const int eb = half * 1024;
    const int ak = (kg & 1) * 8;
    const float* pA = A + (long)eb * RANK;
    float* po = out + (row0 + m16) * D + eb + kg * 4;

#pragma unroll 4
    for (int e = 0; e < 64; ++e) {
        const float* pa = pA + (e * 16 + m16) * RANK + ak;
        f4 a0 = *(const f4*)(pa);
        f4 a1 = *(const f4*)(pa + 4);
        f32x4 o = __builtin_amdgcn_mfma_f32_16x16x32_bf16(
            cvt8(a0, a1), tf, (f32x4){0.f, 0.f, 0.f, 0.f}, 0, 0, 0);
        __builtin_nontemporal_store(o, (f4*)(po + e * 16));
    }
}

extern "C" void kernel_launch(void* const* d_in, const int* in_sizes, int n_in,
                              void* d_out, int out_size, void* d_ws,
                              size_t ws_size, hipStream_t stream) {
    const float* h = (const float*)d_in[0];
    const float* A = (const float*)d_in[1];
    const float* B = (const float*)d_in[2];
    float* out = (float*)d_out;

    const int n_rows = in_sizes[0] / D;   // 16384
    const int blocks = n_rows / 32;       // 512 (2 row-tiles per block)

    hipLaunchKernelGGL(lora_mfma, dim3(blocks), dim3(256), 0, stream,
                       h, A, B, out);
}

// Round 5
// 61.762 us; speedup vs baseline: 1.2879x; 1.2879x over previous
//
#include <hip/hip_runtime.h>
#include <hip/hip_bf16.h>

typedef float f4 __attribute__((ext_vector_type(4)));
typedef short bf16x8 __attribute__((ext_vector_type(8)));

#define D 2048
#define RANK 16
#define TILE 16      // rows per block (one MFMA row-tile)
#define NT 512       // 8 waves

__device__ __forceinline__ short bf16_of(float x) {
    return __builtin_bit_cast(short, __float2bfloat16(x));
}

__device__ __forceinline__ bf16x8 cvt8(f4 lo, f4 hi) {
    bf16x8 r;
    r[0] = bf16_of(lo.x); r[1] = bf16_of(lo.y);
    r[2] = bf16_of(lo.z); r[3] = bf16_of(lo.w);
    r[4] = bf16_of(hi.x); r[5] = bf16_of(hi.y);
    r[6] = bf16_of(hi.z); r[7] = bf16_of(hi.w);
    return r;
}

__device__ __forceinline__ float dot4(f4 a, f4 b) {
    return a.x * b.x + a.y * b.y + a.z * b.z + a.w * b.w;
}

// out = h @ (A@B)^T factored through rank-16.
// Phase1 (MFMA, round-4-verified operand map): per wave, T-partial over its
// K=256 d-slice; lane l ends with acc[i] = T[row=l&15][rank=(l>>4)*4+i].
// Merge 8 wave-partials in fp32 via LDS (one barrier).
// Phase2 (VALU, coalesced): thread owns 4 consecutive e; A-slice is 256
// contiguous bytes prefetched into regs BEFORE phase1; per row 64 FMA; NT
// f4 stores -> each wave stores 1KB contiguous (no partial-line RMW).
__global__ __launch_bounds__(NT, 4)
void lora_mfma2(const float* __restrict__ h, const float* __restrict__ A,
                const float* __restrict__ B, float* __restrict__ out) {
    const int tid  = threadIdx.x;
    const int wave = tid >> 6;
    const int lane = tid & 63;
    const int m16  = lane & 15;
    const int kg   = lane >> 4;
    const long row0 = (long)blockIdx.x * TILE;

    __shared__ f4 ldsT[8][16][4];   // per-wave T partials
    __shared__ f4 tt[16][4];        // merged t[row][rank-quad], fp32

    // ---- prefetch A slice for phase2 (in flight during phase1) ----------
    // Ae[j][q] = A[(tid*4+j)*RANK + q*4 .. +3]  (256B contiguous per thread)
    f4 Ae[4][4];
#pragma unroll
    for (int j = 0; j < 4; ++j)
#pragma unroll
        for (int q = 0; q < 4; ++q)
            Ae[j][q] = *(const f4*)(A + (long)(tid * 4 + j) * RANK + q * 4);

    // ---- phase 1: per-wave MFMA over d-slice [wave*256, wave*256+256) ----
    const float* pB = B + (long)m16 * D + wave * 256 + kg * 8;
    const float* ph = h + (row0 + m16) * D + wave * 256 + kg * 8;

    f4 acc = {0.f, 0.f, 0.f, 0.f};
#pragma unroll
    for (int s = 0; s < 8; ++s) {
        f4 a0 = *(const f4*)(pB + s * 32);
        f4 a1 = *(const f4*)(pB + s * 32 + 4);
        f4 b0 = *(const f4*)(ph + s * 32);
        f4 b1 = *(const f4*)(ph + s * 32 + 4);
        acc = __builtin_amdgcn_mfma_f32_16x16x32_bf16(
            cvt8(a0, a1), cvt8(b0, b1), acc, 0, 0, 0);
    }
    ldsT[wave][m16][kg] = acc;
    __syncthreads();

    // ---- merge 8 wave-partials (fp32) --------------------------------
    if (tid < 64) {
        const int r = tid >> 2, q = tid & 3;
        f4 s = ldsT[0][r][q];
#pragma unroll
        for (int w = 1; w < 8; ++w) s += ldsT[w][r][q];
        tt[r][q] = s;
    }
    __syncthreads();

    // ---- phase 2: out[row][e0..e0+3] for 16 rows, coalesced NT stores ----
    float* po = out + row0 * D + tid * 4;
#pragma unroll
    for (int r = 0; r < TILE; ++r) {
        const f4 t0 = tt[r][0], t1 = tt[r][1], t2 = tt[r][2], t3 = tt[r][3];
        f4 res;
        res.x = dot4(t0, Ae[0][0]) + dot4(t1, Ae[0][1]) +
                dot4(t2, Ae[0][2]) + dot4(t3, Ae[0][3]);
        res.y = dot4(t0, Ae[1][0]) + dot4(t1, Ae[1][1]) +
                dot4(t2, Ae[1][2]) + dot4(t3, Ae[1][3]);
        res.z = dot4(t0, Ae[2][0]) + dot4(t1, Ae[2][1]) +
                dot4(t2, Ae[2][2]) + dot4(t3, Ae[2][3]);
        res.w = dot4(t0, Ae[3][0]) + dot4(t1, Ae[3][1]) +
                dot4(t2, Ae[3][2]) + dot4(t3, Ae[3][3]);
        __builtin_nontemporal_store(res, (f4*)(po + (long)r * D));
    }
}

extern "C" void kernel_launch(void* const* d_in, const int* in_sizes, int n_in,
                              void* d_out, int out_size, void* d_ws,
                              size_t ws_size, hipStream_t stream) {
    const float* h = (const float*)d_in[0];
    const float* A = (const float*)d_in[1];
    const float* B = (const float*)d_in[2];
    float* out = (float*)d_out;

    const int n_rows = in_sizes[0] / D;   // 16384
    const int blocks = n_rows / TILE;     // 1024

    hipLaunchKernelGGL(lora_mfma2, dim3(blocks), dim3(NT), 0, stream,
                       h, A, B, out);
}